// Round 1
// baseline (4035.282 us; speedup 1.0000x reference)
//
#include <hip/hip_runtime.h>
#include <math.h>

typedef unsigned short u16;
typedef unsigned long long u64;

#define T_TOK 8192
#define DDIM  2048
#define IDIM  1024
#define NEXP  32
#define TOPK  8

using short8 = __attribute__((ext_vector_type(8))) short;
using f32x4  = __attribute__((ext_vector_type(4))) float;

// ---------- bf16 helpers (manual RNE, no header-version risk) ----------
__device__ __forceinline__ u16 f2bf(float f) {
    unsigned u = __float_as_uint(f);
    unsigned r = 0x7FFFu + ((u >> 16) & 1u);
    u += r;
    return (u16)(u >> 16);
}
__device__ __forceinline__ float bf2f(u16 h) {
    return __uint_as_float(((unsigned)h) << 16);
}

// ---------- async global->LDS 16B ----------
__device__ __forceinline__ void gl2lds16(const u16* g, u16* l) {
    __builtin_amdgcn_global_load_lds((__attribute__((address_space(1))) void*)g,
                                     (__attribute__((address_space(3))) void*)l,
                                     16, 0, 0);
}

// ---------- workspace layout ----------
constexpr size_t OFF_XB   = 0;
constexpr size_t SZ_XB    = (size_t)T_TOK * DDIM * 2;          // 33,554,432
constexpr size_t OFF_WGT  = OFF_XB + SZ_XB;
constexpr size_t SZ_W     = (size_t)NEXP * DDIM * IDIM * 2;    // 134,217,728
constexpr size_t OFF_WUT  = OFF_WGT + SZ_W;
constexpr size_t OFF_WDT  = OFF_WUT + SZ_W;
constexpr size_t OFF_G    = OFF_WDT + SZ_W;
constexpr size_t SZ_GH    = (size_t)T_TOK * TOPK * IDIM * 2;   // 134,217,728
constexpr size_t OFF_H    = OFF_G + SZ_GH;
constexpr size_t OFF_TOPI = OFF_H + SZ_GH;
constexpr size_t OFF_TOPW = OFF_TOPI + (size_t)T_TOK * TOPK * 4;
constexpr size_t OFF_LIST = OFF_TOPW + (size_t)T_TOK * TOPK * 4;
constexpr size_t OFF_WL   = OFF_LIST + (size_t)T_TOK * TOPK * 4;
constexpr size_t OFF_CTRL = OFF_WL + (size_t)T_TOK * TOPK * 4;

// ---------- x fp32 -> bf16 ----------
__global__ __launch_bounds__(256) void cvt_x_kernel(const float* __restrict__ x,
                                                    u16* __restrict__ xb) {
    int i = (blockIdx.x * 256 + threadIdx.x) * 4;
    float4 v = *(const float4*)(x + i);
    u64 pk = (u64)f2bf(v.x) | ((u64)f2bf(v.y) << 16) |
             ((u64)f2bf(v.z) << 32) | ((u64)f2bf(v.w) << 48);
    *(u64*)(xb + i) = pk;
}

// ---------- per-expert-slice transpose + fp32->bf16 : dst[n][m] = src[m][n] ----------
__global__ __launch_bounds__(256) void transpose_cvt_kernel(const float* __restrict__ src,
                                                            u16* __restrict__ dst,
                                                            int M, int N) {
    __shared__ float tile[32][33];
    const size_t slice = (size_t)M * N;
    const float* s = src + (size_t)blockIdx.z * slice;
    u16* d = dst + (size_t)blockIdx.z * slice;
    int c0 = blockIdx.x * 32, r0 = blockIdx.y * 32;
    int tx = threadIdx.x & 31, ty = threadIdx.x >> 5;   // 32 x 8
#pragma unroll
    for (int i = 0; i < 32; i += 8)
        tile[ty + i][tx] = s[(size_t)(r0 + ty + i) * N + c0 + tx];
    __syncthreads();
#pragma unroll
    for (int i = 0; i < 32; i += 8)
        d[(size_t)(c0 + ty + i) * M + r0 + tx] = f2bf(tile[tx][ty + i]);
}

// ---------- router: fp32 logits, full softmax (aux), top-8 + softmax weights ----------
__global__ __launch_bounds__(256) void router_kernel(const float* __restrict__ x,
                                                     const float* __restrict__ Wgate,
                                                     int* __restrict__ topi,
                                                     float* __restrict__ topw,
                                                     int* __restrict__ counts,
                                                     float* __restrict__ probs_sum) {
    __shared__ float part[8][32];
    __shared__ float lg[32];
    __shared__ float ex[32];
    __shared__ int   sel[8];
    __shared__ float rw[8];
    __shared__ float inv_se;

    const int t = blockIdx.x;
    const int tid = threadIdx.x;
    const int e = tid & 31, j = tid >> 5;
    const float* xr = x + (size_t)t * DDIM;
    float p = 0.f;
    const int d0 = j * (DDIM / 8);
    for (int d = d0; d < d0 + DDIM / 8; ++d)
        p += xr[d] * Wgate[(size_t)d * NEXP + e];
    part[j][e] = p;
    __syncthreads();
    if (tid < 32) {
        float s = 0.f;
#pragma unroll
        for (int q = 0; q < 8; q++) s += part[q][tid];
        lg[tid] = s;
    }
    __syncthreads();
    if (tid == 0) {
        unsigned used = 0;
        float tv[TOPK]; int ti[TOPK];
        for (int k = 0; k < TOPK; k++) {
            float best = -3.4e38f; int bi = 0;
            for (int i = 0; i < NEXP; i++) {
                float v = lg[i];
                if (!((used >> i) & 1u) && v > best) { best = v; bi = i; }
            }
            used |= 1u << bi; tv[k] = best; ti[k] = bi;
        }
        float mx = tv[0];
        float ev[TOPK]; float s = 0.f;
        for (int k = 0; k < TOPK; k++) { ev[k] = expf(tv[k] - mx); s += ev[k]; }
        for (int k = 0; k < TOPK; k++) { rw[k] = ev[k] / s; sel[k] = ti[k]; }
        float se = 0.f;
        for (int i = 0; i < NEXP; i++) { float v = expf(lg[i] - mx); ex[i] = v; se += v; }
        inv_se = 1.f / se;
    }
    __syncthreads();
    if (tid < 32) atomicAdd(&probs_sum[tid], ex[tid] * inv_se);
    if (tid < TOPK) {
        topi[t * TOPK + tid] = sel[tid];
        topw[t * TOPK + tid] = rw[tid];
        atomicAdd(&counts[sel[tid]], 1);
    }
}

// ---------- offsets + aux loss ----------
__global__ void finalize_kernel(const int* __restrict__ counts,
                                const float* __restrict__ probs_sum,
                                int* __restrict__ offsets,
                                float* __restrict__ aux_out) {
    if (threadIdx.x == 0 && blockIdx.x == 0) {
        int acc = 0; float aux = 0.f;
        for (int e = 0; e < NEXP; e++) {
            offsets[e] = acc; acc += counts[e];
            aux += probs_sum[e] * (float)counts[e];
        }
        *aux_out = aux / ((float)T_TOK * (float)T_TOK);
    }
}

// ---------- scatter (t,k) pairs into compacted per-expert lists ----------
__global__ __launch_bounds__(256) void scatter_kernel(const int* __restrict__ topi,
                                                      const float* __restrict__ topw,
                                                      const int* __restrict__ offsets,
                                                      int* __restrict__ cursor,
                                                      int* __restrict__ list,
                                                      float* __restrict__ wlist) {
    int i = blockIdx.x * 256 + threadIdx.x;
    int e = topi[i];
    int pos = atomicAdd(&cursor[e], 1);
    int idx = offsets[e] + pos;
    list[idx] = i >> 3;
    wlist[idx] = topw[i];
}

// ---------- grouped GEMM: C = A(gathered) @ B^T(e), 128x128 tile, BK=64 ----------
// MODE 0: A=xb(gather), B=WgT -> G = bf16(silu(c))
// MODE 1: A=xb(gather), B=WuT -> H = bf16(G * c * w)
// MODE 2: A=H(direct),  B=WdT -> atomicAdd(out[tok], c)
template <int MODE>
__global__ __launch_bounds__(256)
void moe_gemm(const u16* __restrict__ A, const u16* __restrict__ B,
              const int* __restrict__ list, const float* __restrict__ wlist,
              const int* __restrict__ counts, const int* __restrict__ offsets,
              u16* __restrict__ Gbuf, u16* __restrict__ Hbuf,
              float* __restrict__ Out, int Kdim, int Ncols) {
    const int e = blockIdx.z;
    const int cnt = counts[e];
    const int m0 = blockIdx.x * 128;
    if (m0 >= cnt) return;
    const int off = offsets[e];
    const int n0 = blockIdx.y * 128;

    __shared__ __attribute__((aligned(16))) u16 As[128 * 64];
    __shared__ __attribute__((aligned(16))) u16 Bs[128 * 64];

    const int tid = threadIdx.x;
    const int w = tid >> 6, lane = tid & 63;
    const int wm = (w >> 1) * 64, wn = (w & 1) * 64;

    // staging: wave w stages rows [w*32, w*32+32) in 4 insts of 8 rows; 16B/lane
    const int srow = w * 32 + (lane >> 3);
    const int scol = (lane & 7) * 8;
    const u16* aptr[4];
    const u16* bptr[4];
    u16* aldsb[4];
    u16* bldsb[4];
#pragma unroll
    for (int q = 0; q < 4; q++) {
        int rl = srow + q * 8;
        int gr = m0 + rl; if (gr > cnt - 1) gr = cnt - 1;
        size_t arow;
        if (MODE == 2) arow = (size_t)(off + gr);
        else           arow = (size_t)list[off + gr];
        aptr[q] = A + arow * (size_t)Kdim + scol;
        bptr[q] = B + ((size_t)e * Ncols + n0 + rl) * (size_t)Kdim + scol;
        aldsb[q] = &As[(w * 32 + q * 8) * 64];
        bldsb[q] = &Bs[(w * 32 + q * 8) * 64];
    }

    f32x4 acc[4][4];
#pragma unroll
    for (int i = 0; i < 4; i++)
#pragma unroll
        for (int j = 0; j < 4; j++) acc[i][j] = (f32x4){0.f, 0.f, 0.f, 0.f};

    const int fr = lane & 15, fq = lane >> 4;

    for (int k0 = 0; k0 < Kdim; k0 += 64) {
#pragma unroll
        for (int q = 0; q < 4; q++) {
            gl2lds16(aptr[q] + k0, aldsb[q]);
            gl2lds16(bptr[q] + k0, bldsb[q]);
        }
        __syncthreads();
#pragma unroll
        for (int kk = 0; kk < 64; kk += 32) {
            short8 af[4], bfv[4];
#pragma unroll
            for (int i = 0; i < 4; i++)
                af[i] = *(const short8*)&As[(wm + i * 16 + fr) * 64 + kk + fq * 8];
#pragma unroll
            for (int j = 0; j < 4; j++)
                bfv[j] = *(const short8*)&Bs[(wn + j * 16 + fr) * 64 + kk + fq * 8];
#pragma unroll
            for (int i = 0; i < 4; i++)
#pragma unroll
                for (int j = 0; j < 4; j++)
                    acc[i][j] = __builtin_amdgcn_mfma_f32_16x16x32_bf16(af[i], bfv[j], acc[i][j], 0, 0, 0);
        }
        __syncthreads();
    }

    // epilogue: D[m= fq*4+r ][n= fr] per 16x16 tile
#pragma unroll
    for (int i = 0; i < 4; i++) {
#pragma unroll
        for (int r = 0; r < 4; r++) {
            const int m = wm + i * 16 + fq * 4 + r;
            const int gr = m0 + m;
            if (gr >= cnt) continue;
            if (MODE == 0) {
                u16* gp = Gbuf + (size_t)(off + gr) * IDIM + n0;
#pragma unroll
                for (int j = 0; j < 4; j++) {
                    float v = acc[i][j][r];
                    gp[wn + j * 16 + fr] = f2bf(v / (1.f + __expf(-v)));
                }
            } else if (MODE == 1) {
                const size_t base = (size_t)(off + gr) * IDIM + n0;
                const float wgt = wlist[off + gr];
#pragma unroll
                for (int j = 0; j < 4; j++) {
                    int n = wn + j * 16 + fr;
                    float g = bf2f(Gbuf[base + n]);
                    Hbuf[base + n] = f2bf(g * acc[i][j][r] * wgt);
                }
            } else {
                const int tok = list[off + gr];
                float* op = Out + (size_t)tok * DDIM + n0;
#pragma unroll
                for (int j = 0; j < 4; j++)
                    atomicAdd(op + wn + j * 16 + fr, acc[i][j][r]);
            }
        }
    }
}

extern "C" void kernel_launch(void* const* d_in, const int* in_sizes, int n_in,
                              void* d_out, int out_size, void* d_ws, size_t ws_size,
                              hipStream_t stream) {
    (void)in_sizes; (void)n_in; (void)ws_size;
    const float* x     = (const float*)d_in[0];
    const float* Wgate = (const float*)d_in[1];
    const float* Wg    = (const float*)d_in[2];
    const float* Wu    = (const float*)d_in[3];
    const float* Wd    = (const float*)d_in[4];
    float* out = (float*)d_out;
    char* ws = (char*)d_ws;

    u16* xb    = (u16*)(ws + OFF_XB);
    u16* WgT   = (u16*)(ws + OFF_WGT);
    u16* WuT   = (u16*)(ws + OFF_WUT);
    u16* WdT   = (u16*)(ws + OFF_WDT);
    u16* Gb    = (u16*)(ws + OFF_G);
    u16* Hb    = (u16*)(ws + OFF_H);
    int* topi  = (int*)(ws + OFF_TOPI);
    float* topw = (float*)(ws + OFF_TOPW);
    int* list  = (int*)(ws + OFF_LIST);
    float* wlist = (float*)(ws + OFF_WL);
    int* counts  = (int*)(ws + OFF_CTRL);
    int* cursor  = counts + 32;
    int* offsets = counts + 64;
    float* probs_sum = (float*)(counts + 96);

    hipMemsetAsync(ws + OFF_CTRL, 0, 512, stream);
    hipMemsetAsync(d_out, 0, (size_t)out_size * sizeof(float), stream);

    cvt_x_kernel<<<(T_TOK * DDIM / 4) / 256, 256, 0, stream>>>(x, xb);
    transpose_cvt_kernel<<<dim3(IDIM / 32, DDIM / 32, NEXP), 256, 0, stream>>>(Wg, WgT, DDIM, IDIM);
    transpose_cvt_kernel<<<dim3(IDIM / 32, DDIM / 32, NEXP), 256, 0, stream>>>(Wu, WuT, DDIM, IDIM);
    transpose_cvt_kernel<<<dim3(DDIM / 32, IDIM / 32, NEXP), 256, 0, stream>>>(Wd, WdT, IDIM, DDIM);

    router_kernel<<<T_TOK, 256, 0, stream>>>(x, Wgate, topi, topw, counts, probs_sum);
    finalize_kernel<<<1, 64, 0, stream>>>(counts, probs_sum, offsets, out + (size_t)T_TOK * DDIM);
    scatter_kernel<<<(T_TOK * TOPK) / 256, 256, 0, stream>>>(topi, topw, offsets, cursor, list, wlist);

    moe_gemm<0><<<dim3(64, IDIM / 128, NEXP), 256, 0, stream>>>(xb, WgT, list, wlist, counts, offsets, Gb, Hb, out, DDIM, IDIM);
    moe_gemm<1><<<dim3(64, IDIM / 128, NEXP), 256, 0, stream>>>(xb, WuT, list, wlist, counts, offsets, Gb, Hb, out, DDIM, IDIM);
    moe_gemm<2><<<dim3(64, DDIM / 128, NEXP), 256, 0, stream>>>(Hb, WdT, list, wlist, counts, offsets, Gb, Hb, out, IDIM, DDIM);
}